// Round 6
// baseline (92.821 us; speedup 1.0000x reference)
//
#include <hip/hip_runtime.h>

#define N 64
#define MARGIN 0.1f
#define WAVES_PER_BLOCK 4
#define NBLOCKS 2048

// closed form (verified R2..R16, absmax 0.0): row_loss = sum_e u_e*(q_e - p_e)
//   p_e = #{k: lab_k < lab_e},  u_e = sc_e - MARGIN*p_e,  q_e = #{k: u_k < u_e}
//
// R17: ALL-REGISTER broadcast via v_readlane.
//   History: R11 (80.2us) re-read the row via L1 float4 broadcasts (pass1)
//   and an LDS round-trip (pass2). R16 moved pass1 to LDS -> LDS pipe
//   (per-CU, shared by 4 SIMDs) became the serializer (~33 LDS ops/row +
//   2 lgkm drains). Insight: the row IS ALREADY IN REGISTERS -- lane e
//   holds labv_e and u_e. Broadcasting element k needs no memory pipe:
//     v_readlane_b32 s, v, k   (k compile-time, loop unrolled)
//     v_sub_f32 t, s, v        (sgpr src0)  + ashr + add  (sign-bit count)
//   Zero in-loop memory traffic: no ubuf, no drains, no broadcasts. Per
//   row: 2 coalesced per-lane loads (prefetched a full row ahead) + ~530
//   VALU. Pure-issue floor ~14us/SIMD; nothing left to stall on.
//   4 independent accumulator chains hide the readlane->sgpr-read hazard.

#define RL(dst, src, k) \
    asm("v_readlane_b32 %0, %1, %2" : "=s"(dst) : "v"(src), "i"(k))

// one 4-element step of the rank loop: 4 readlanes feeding 4 chains
#define RANKSTEP(val, c0, c1, c2, c3, k)                 \
    do {                                                 \
        float _s0, _s1, _s2, _s3;                        \
        RL(_s0, val, (k) + 0);                           \
        RL(_s1, val, (k) + 1);                           \
        RL(_s2, val, (k) + 2);                           \
        RL(_s3, val, (k) + 3);                           \
        c0 += __float_as_int(_s0 - (val)) >> 31;         \
        c1 += __float_as_int(_s1 - (val)) >> 31;         \
        c2 += __float_as_int(_s2 - (val)) >> 31;         \
        c3 += __float_as_int(_s3 - (val)) >> 31;         \
    } while (0)

__global__ __launch_bounds__(256) void mmrl_partial(const float* __restrict__ scores,
                                                    const float* __restrict__ labels,
                                                    float* __restrict__ partial,
                                                    int rows) {
    __shared__ float wsum[WAVES_PER_BLOCK];

    const int lane = threadIdx.x & 63;
    const int w    = threadIdx.x >> 6;
    const int gwave = blockIdx.x * WAVES_PER_BLOCK + w;
    const int nwaves = NBLOCKS * WAVES_PER_BLOCK;

    float acc = 0.0f;

    if (gwave < rows) {   // wave-uniform guard
        // ---- prologue: row0 per-lane copies (coalesced) ----
        const int base0 = __builtin_amdgcn_readfirstlane(gwave) * N;
        float labv = labels[base0 + lane];
        float scv  = scores[base0 + lane];

        for (int row = gwave; row < rows; row += nwaves) {
            // ---- prefetch next row's per-lane copies (consumed at bottom;
            //      a full row of VALU work hides their HBM latency) ----
            const int next  = row + nwaves;
            const int nbase = __builtin_amdgcn_readfirstlane(next < rows ? next : row) * N;
            const float labv_n = labels[nbase + lane];
            const float scv_n  = scores[nbase + lane];

            // ---- pass 1: label rank p, pure readlane broadcasts ----
            int p0 = 0, p1 = 0, p2 = 0, p3 = 0;      // accumulate 0 / -1
            #pragma unroll
            for (int k = 0; k < N; k += 4)
                RANKSTEP(labv, p0, p1, p2, p3, k);
            const int pv = -((p0 + p1) + (p2 + p3));

            const float u = fmaf(-MARGIN, (float)pv, scv);

            // ---- pass 2: u rank q, pure readlane broadcasts ----
            int q0 = 0, q1 = 0, q2 = 0, q3 = 0;
            #pragma unroll
            for (int k = 0; k < N; k += 4)
                RANKSTEP(u, q0, q1, q2, q3, k);
            const int qv = -((q0 + q1) + (q2 + q3));

            acc = fmaf(u, (float)(qv - pv), acc);

            labv = labv_n;   // rotate prefetched copies into place
            scv  = scv_n;
        }
    }

    // ---- wave reduction ----
    #pragma unroll
    for (int off = 32; off > 0; off >>= 1)
        acc += __shfl_down(acc, off, 64);

    if (lane == 0) wsum[w] = acc;
    __syncthreads();
    if (threadIdx.x == 0) {
        float s = 0.0f;
        #pragma unroll
        for (int i = 0; i < WAVES_PER_BLOCK; ++i) s += wsum[i];
        partial[blockIdx.x] = s;          // plain store, no atomic, no fence
    }
}

__global__ __launch_bounds__(256) void mmrl_reduce(const float* __restrict__ partial,
                                                   float* __restrict__ out,
                                                   int npartial, float inv_rows) {
    const int t = threadIdx.x;
    float s = 0.0f;
    for (int i = t; i < npartial; i += 256)
        s += partial[i];
    #pragma unroll
    for (int off = 32; off > 0; off >>= 1)
        s += __shfl_down(s, off, 64);
    __shared__ float wsum[4];
    if ((t & 63) == 0) wsum[t >> 6] = s;
    __syncthreads();
    if (t == 0)
        out[0] = (wsum[0] + wsum[1] + wsum[2] + wsum[3]) * inv_rows;
}

extern "C" void kernel_launch(void* const* d_in, const int* in_sizes, int n_in,
                              void* d_out, int out_size, void* d_ws, size_t ws_size,
                              hipStream_t stream) {
    const float* scores = (const float*)d_in[0];
    const float* labels = (const float*)d_in[1];
    float* out = (float*)d_out;
    float* partial = (float*)d_ws;        // 2048 floats = 8 KB << ws_size
    const int rows = in_sizes[0] / N;     // 32768

    mmrl_partial<<<NBLOCKS, 256, 0, stream>>>(scores, labels, partial, rows);
    mmrl_reduce<<<1, 256, 0, stream>>>(partial, out, NBLOCKS, 1.0f / (float)rows);
}

// Round 7
// 80.929 us; speedup vs baseline: 1.1470x; 1.1470x over previous
//
#include <hip/hip_runtime.h>

#define N 64
#define MARGIN 0.1f
#define WAVES_PER_BLOCK 4
#define NBLOCKS 2048

// closed form (verified R2..R16, absmax 0.0): row_loss = sum_e u_e*(q_e - p_e)
//   p_e = #{k: lab_k < lab_e},  u_e = sc_e - MARGIN*p_e,  q_e = #{k: u_k < u_e}
//
// R18: explicit scalar-pipeline pass 1 with one-row prefetch distance.
//   R11 (80.2us best) already had pass1 on (compiler-derived) scalar loads,
//   but they issue inside the consuming iteration, pinned by the "memory"
//   drain -> exposed K$/L2 latency each row. R18 issues 4x s_load_dwordx16
//   (volatile asm, 64 labels -> 64 SGPRs) for row r+1 at the TOP of
//   iteration r; pass1 is then pure v_sub(sgpr,vgpr)+ashr+add on data
//   loaded a full iteration earlier. Zero in-loop memory in pass1.
//   Counter discipline (SMEM completes out-of-order vs DS, lgkmcnt is
//   shared): loop-top lgkmcnt(0) = no outstanding DS when s_loads issue;
//   mid drain (after ds_write u) retires all SMEM before pass2's
//   compiler-counted ds_reads. One drain pair per row, both off the
//   critical path.
//   Compute: R11's proven sign-bit form, 4 independent chains. No
//   launch-bounds min-waves clamp (R15 lesson: VGPR=32 serializes loads).

typedef float f16v __attribute__((ext_vector_type(16)));

#define SLOAD16(dst, ptr, off) \
    asm volatile("s_load_dwordx16 %0, %1, %2" : "=&s"(dst) : "s"(ptr), "i"(off))

// 16 comparisons from one SGPR tuple, rotated over 4 independent chains
#define CMP16(sg, val, c0, c1, c2, c3)                  \
    do {                                                \
        c0 += __float_as_int((sg)[0]  - (val)) >> 31;   \
        c1 += __float_as_int((sg)[1]  - (val)) >> 31;   \
        c2 += __float_as_int((sg)[2]  - (val)) >> 31;   \
        c3 += __float_as_int((sg)[3]  - (val)) >> 31;   \
        c0 += __float_as_int((sg)[4]  - (val)) >> 31;   \
        c1 += __float_as_int((sg)[5]  - (val)) >> 31;   \
        c2 += __float_as_int((sg)[6]  - (val)) >> 31;   \
        c3 += __float_as_int((sg)[7]  - (val)) >> 31;   \
        c0 += __float_as_int((sg)[8]  - (val)) >> 31;   \
        c1 += __float_as_int((sg)[9]  - (val)) >> 31;   \
        c2 += __float_as_int((sg)[10] - (val)) >> 31;   \
        c3 += __float_as_int((sg)[11] - (val)) >> 31;   \
        c0 += __float_as_int((sg)[12] - (val)) >> 31;   \
        c1 += __float_as_int((sg)[13] - (val)) >> 31;   \
        c2 += __float_as_int((sg)[14] - (val)) >> 31;   \
        c3 += __float_as_int((sg)[15] - (val)) >> 31;   \
    } while (0)

__global__ __launch_bounds__(256) void mmrl_partial(const float* __restrict__ scores,
                                                    const float* __restrict__ labels,
                                                    float* __restrict__ partial,
                                                    int rows) {
    __shared__ float ubuf[WAVES_PER_BLOCK][N];
    __shared__ float wsum[WAVES_PER_BLOCK];

    const int lane = threadIdx.x & 63;
    const int w    = threadIdx.x >> 6;
    const int gwave = blockIdx.x * WAVES_PER_BLOCK + w;
    const int nwaves = NBLOCKS * WAVES_PER_BLOCK;

    float acc = 0.0f;

    if (gwave < rows) {   // wave-uniform guard (gwave uniform within wave)
        // ---- prologue: row0 labels -> SGPRs; row0 per-lane copies ----
        const int base0 = __builtin_amdgcn_readfirstlane(gwave) * N;
        f16v sg0, sg1, sg2, sg3;
        {
            const float* rp = labels + base0;
            SLOAD16(sg0, rp, 0);
            SLOAD16(sg1, rp, 64);
            SLOAD16(sg2, rp, 128);
            SLOAD16(sg3, rp, 192);
        }
        float labv = labels[base0 + lane];
        float scv  = scores[base0 + lane];
        asm volatile("s_waitcnt lgkmcnt(0)" ::: "memory");  // row0 sgprs ready

        for (int row = gwave; row < rows; row += nwaves) {
            // ---- top: issue NEXT row's scalar loads + per-lane prefetch.
            //      (no outstanding DS here: previous pass2 fully drained) ----
            const int next  = row + nwaves;
            const int nrow  = __builtin_amdgcn_readfirstlane(next < rows ? next : row);
            const float* np = labels + nrow * N;
            f16v ng0, ng1, ng2, ng3;
            SLOAD16(ng0, np, 0);
            SLOAD16(ng1, np, 64);
            SLOAD16(ng2, np, 128);
            SLOAD16(ng3, np, 192);
            const float labv_n = labels[nrow * N + lane];   // vector path (vmcnt)
            const float scv_n  = scores[nrow * N + lane];

            // ---- pass 1: label rank p -- pure VALU on current row's SGPRs ----
            int p0 = 0, p1 = 0, p2 = 0, p3 = 0;       // accumulate 0 / -1
            CMP16(sg0, labv, p0, p1, p2, p3);
            CMP16(sg1, labv, p0, p1, p2, p3);
            CMP16(sg2, labv, p0, p1, p2, p3);
            CMP16(sg3, labv, p0, p1, p2, p3);
            const int pv = -((p0 + p1) + (p2 + p3));

            const float u = fmaf(-MARGIN, (float)pv, scv);

            // ---- u broadcast staging + single drain:
            //      retires this row's ds_write AND next row's s_loads
            //      (s_loads had all of pass1 to land) ----
            ubuf[w][lane] = u;
            asm volatile("s_waitcnt lgkmcnt(0)" ::: "memory");

            // ---- pass 2: u rank q (LDS uniform b128 broadcasts; only DS
            //      outstanding from here -> compiler's counted waits safe) ----
            const float4* U4 = (const float4*)ubuf[w];
            int q0 = 0, q1 = 0, q2 = 0, q3 = 0;
            #pragma unroll
            for (int kk = 0; kk < N / 4; ++kk) {
                const float4 c = U4[kk];
                q0 += __float_as_int(c.x - u) >> 31;
                q1 += __float_as_int(c.y - u) >> 31;
                q2 += __float_as_int(c.z - u) >> 31;
                q3 += __float_as_int(c.w - u) >> 31;
            }
            const int qv = -((q0 + q1) + (q2 + q3));

            acc = fmaf(u, (float)(qv - pv), acc);

            // ---- rotate prefetched state into place ----
            sg0 = ng0; sg1 = ng1; sg2 = ng2; sg3 = ng3;
            labv = labv_n;
            scv  = scv_n;
        }
    }

    // ---- wave reduction ----
    #pragma unroll
    for (int off = 32; off > 0; off >>= 1)
        acc += __shfl_down(acc, off, 64);

    if (lane == 0) wsum[w] = acc;
    __syncthreads();
    if (threadIdx.x == 0) {
        float s = 0.0f;
        #pragma unroll
        for (int i = 0; i < WAVES_PER_BLOCK; ++i) s += wsum[i];
        partial[blockIdx.x] = s;          // plain store, no atomic, no fence
    }
}

__global__ __launch_bounds__(256) void mmrl_reduce(const float* __restrict__ partial,
                                                   float* __restrict__ out,
                                                   int npartial, float inv_rows) {
    const int t = threadIdx.x;
    float s = 0.0f;
    for (int i = t; i < npartial; i += 256)
        s += partial[i];
    #pragma unroll
    for (int off = 32; off > 0; off >>= 1)
        s += __shfl_down(s, off, 64);
    __shared__ float wsum[4];
    if ((t & 63) == 0) wsum[t >> 6] = s;
    __syncthreads();
    if (t == 0)
        out[0] = (wsum[0] + wsum[1] + wsum[2] + wsum[3]) * inv_rows;
}

extern "C" void kernel_launch(void* const* d_in, const int* in_sizes, int n_in,
                              void* d_out, int out_size, void* d_ws, size_t ws_size,
                              hipStream_t stream) {
    const float* scores = (const float*)d_in[0];
    const float* labels = (const float*)d_in[1];
    float* out = (float*)d_out;
    float* partial = (float*)d_ws;        // 2048 floats = 8 KB << ws_size
    const int rows = in_sizes[0] / N;     // 32768

    mmrl_partial<<<NBLOCKS, 256, 0, stream>>>(scores, labels, partial, rows);
    mmrl_reduce<<<1, 256, 0, stream>>>(partial, out, NBLOCKS, 1.0f / (float)rows);
}